// Round 10
// baseline (366.332 us; speedup 1.0000x reference)
//
#include <hip/hip_runtime.h>
#include <stdint.h>

#define NROWS   32768
#define XDIM    1024
#define NCB     8
#define NCODE   1024
#define CDIM    128

#define CHUNK   32
#define NCHUNK  (NCODE / CHUNK)   // 32

// 8 waves * 32 rows = 256 rows/block, 1024 blocks
#define NTH     512
#define ROWS_PB 256
#define RPW     32

typedef _Float16 h8 __attribute__((ext_vector_type(8)));
typedef float    f4 __attribute__((ext_vector_type(4)));

#define LO_SCALE 2048.0f
#define LO_INV   4.8828125e-4f    // 2^-11

// ws: per (m,chunk) 16 KB blob: [hilo][g<16][k<32][8 halfs], then c2[8192] f32
#define BLOB_BYTES 16384
#define WS_C2   ((size_t)NCB * NCHUNK * BLOB_BYTES)       // 4 MB
#define WS_NEED (WS_C2 + (size_t)NCB * NCODE * 4)

__device__ __forceinline__ void gload_lds16(const void* g, void* l) {
    __builtin_amdgcn_global_load_lds(
        (const __attribute__((address_space(1))) void*)g,
        (__attribute__((address_space(3))) void*)l, 16, 0, 0);
}

// =====================================================================
// Precompute (r5/r7/r8-proven): transposed chunk blobs + fp64 c2.
// blob(m,c) byte (hilo*8192 + g*512 + k*16 + i*2) = f16 of cb[m][c*32+k][g*8+i]
// =====================================================================
__global__ __launch_bounds__(256)
void precompute_kernel(const float* __restrict__ cb, uint8_t* __restrict__ ws)
{
    float* c2 = (float*)(ws + WS_C2);

    const int idx  = blockIdx.x * 256 + threadIdx.x;  // 131072 = 8192 codes * 16 groups
    const int g    = idx & 15;
    const int code = idx >> 4;          // m*1024 + kk
    const int mm   = code >> 10;
    const int c    = (code & 1023) >> 5;
    const int k    = code & 31;

    const float* src = cb + (size_t)code * CDIM + g * 8;
    float v[8];
    *(f4*)&v[0] = *(const f4*)src;
    *(f4*)&v[4] = *(const f4*)(src + 4);

    _Float16 hh[8], ll[8];
    double s = 0.0;
    #pragma unroll
    for (int i = 0; i < 8; ++i) {
        _Float16 h = (_Float16)v[i];
        float    r = v[i] - (float)h;
        hh[i] = h; ll[i] = (_Float16)(r * LO_SCALE);
        s = fma((double)v[i], (double)v[i], s);
    }
    uint8_t* blob = ws + ((size_t)(mm * NCHUNK + c)) * BLOB_BYTES;
    *(h8*)(blob + g * 512 + k * 16)        = *(h8*)hh;
    *(h8*)(blob + 8192 + g * 512 + k * 16) = *(h8*)ll;

    #pragma unroll
    for (int mask = 1; mask <= 8; mask <<= 1)
        s += __shfl_xor(s, mask, 16);
    if (g == 0) c2[code] = (float)s;
}

// =====================================================================
// Fast main kernel: r9 shell + zero-conflict blob LDS + fenced 1-ahead reads
// =====================================================================
__global__ __launch_bounds__(NTH, 4)
void quant_fast(const float* __restrict__ x, const float* __restrict__ cb,
                const uint8_t* __restrict__ ws, float* __restrict__ out)
{
    __shared__ __align__(16) _Float16 S[2][2][16][CHUNK][8]; // 32 KB [buf][hilo][g][k][8]
    __shared__ float  c2s[NCODE];                            // 4 KB
    __shared__ float  x2s[ROWS_PB];                          // 1 KB
    __shared__ int    idxs[ROWS_PB];                         // 1 KB
    // 38 KB

    const float* c2w = (const float*)(ws + WS_C2);

    const int t    = threadIdx.x;
    const int m    = blockIdx.x & 7;     // one m per XCD (proven r3/r9)
    const int rb   = blockIdx.x >> 3;    // 0..127
    const int row0 = rb * ROWS_PB;

    const int l    = t & 63;
    const int w    = t >> 6;             // wave 0..7, rows w*32..w*32+31
    const int l15  = l & 15;
    const int lh   = l >> 4;             // 0..3

    // ---- staging: pure linear copy, 2 KB per wave (r6-proven addresses) ----
    auto stage = [&](int c, int buf) {
        const uint8_t* src = ws + ((size_t)(m * NCHUNK + c) << 14) + (w << 11) + (l << 4);
        char* dst = (char*)&S[0][0][0][0][0] + buf * 16384 + (w << 11);
        gload_lds16(src,        dst);
        gload_lds16(src + 1024, dst + 1024);
    };

    stage(0, 0);

    // ---- c2 fill from precomputed ----
    if (t < 256) *(f4*)&c2s[t * 4] = *(const f4*)&c2w[m * NCODE + t * 4];

    // ---- x fragments + fused fp64 x2 (proven bit-exact) ----
    h8 xh[2][4], xl[2][4];
    #pragma unroll
    for (int rs = 0; rs < 2; ++rs) {
        const float* xp = x + (size_t)(row0 + w * RPW + rs * 16 + l15) * XDIM + m * CDIM + lh * 8;
        double s = 0.0;
        #pragma unroll
        for (int ks = 0; ks < 4; ++ks) {
            float v[8];
            *(f4*)&v[0] = *(const f4*)(xp + ks * 32);
            *(f4*)&v[4] = *(const f4*)(xp + ks * 32 + 4);
            #pragma unroll
            for (int i = 0; i < 8; ++i) {
                _Float16 h = (_Float16)v[i];
                float    r = v[i] - (float)h;
                xh[rs][ks][i] = h;
                xl[rs][ks][i] = (_Float16)(r * LO_SCALE);
                s = fma((double)v[i], (double)v[i], s);
            }
        }
        s += __shfl_xor(s, 16, 64);
        s += __shfl_xor(s, 32, 64);
        if (lh == 0) x2s[w * RPW + rs * 16 + l15] = (float)s;
    }

    __syncthreads();   // chunk 0 staged, x2s/c2s visible

    float x2r[2][4];
    #pragma unroll
    for (int rs = 0; rs < 2; ++rs)
        #pragma unroll
        for (int j = 0; j < 4; ++j)
            x2r[rs][j] = x2s[w * RPW + rs * 16 + lh * 4 + j];

    float mval[2][4];
    int   midx[2][4];
    #pragma unroll
    for (int rs = 0; rs < 2; ++rs)
        #pragma unroll
        for (int j = 0; j < 4; ++j) { mval[rs][j] = 3.0e38f; midx[rs][j] = 0; }

    // per-lane read base, element units: lane reads g=ks*4+lh, k=cf*16+l15
    const _Float16* Sl = &S[0][0][0][0][0] + (lh * 256 + l15 * 8);

    for (int c = 0; c < NCHUNK; ++c) {
        const int cur = c & 1;
        if (c + 1 < NCHUNK) stage(c + 1, cur ^ 1);   // in flight across whole body

        const _Float16* Sc = Sl + cur * 8192;

        #pragma unroll
        for (int cf = 0; cf < 2; ++cf) {
            f4 accH[2] = {{0,0,0,0},{0,0,0,0}};
            f4 accS[2] = {{0,0,0,0},{0,0,0,0}};

            // 1-ahead prefetched, fenced reads: zero-conflict blob pattern
            h8 bh = *(const h8*)(Sc +        cf * 128);
            h8 bl = *(const h8*)(Sc + 4096 + cf * 128);
            #pragma unroll
            for (int ks = 0; ks < 4; ++ks) {
                h8 bhn, bln;
                if (ks < 3) {
                    bhn = *(const h8*)(Sc +        (ks + 1) * 1024 + cf * 128);
                    bln = *(const h8*)(Sc + 4096 + (ks + 1) * 1024 + cf * 128);
                } else { bhn = bh; bln = bl; }
                accH[0] = __builtin_amdgcn_mfma_f32_16x16x32_f16(xh[0][ks], bh, accH[0], 0, 0, 0);
                accH[1] = __builtin_amdgcn_mfma_f32_16x16x32_f16(xh[1][ks], bh, accH[1], 0, 0, 0);
                accS[0] = __builtin_amdgcn_mfma_f32_16x16x32_f16(xh[0][ks], bl, accS[0], 0, 0, 0);
                accS[0] = __builtin_amdgcn_mfma_f32_16x16x32_f16(xl[0][ks], bh, accS[0], 0, 0, 0);
                accS[1] = __builtin_amdgcn_mfma_f32_16x16x32_f16(xh[1][ks], bl, accS[1], 0, 0, 0);
                accS[1] = __builtin_amdgcn_mfma_f32_16x16x32_f16(xl[1][ks], bh, accS[1], 0, 0, 0);
                asm volatile("" ::: "memory");   // stop batch-hoisting of later reads
                bh = bhn; bl = bln;
            }
            const int   code = c * CHUNK + cf * 16 + l15;
            const float c2v  = c2s[code];
            #pragma unroll
            for (int rs = 0; rs < 2; ++rs)
                #pragma unroll
                for (int j = 0; j < 4; ++j) {
                    float dot = fmaf(accS[rs][j], LO_INV, accH[rs][j]);
                    float d2  = (x2r[rs][j] + c2v) - 2.0f * dot;  // exact proven formula
                    if (d2 < mval[rs][j]) { mval[rs][j] = d2; midx[rs][j] = code; }
                }
        }
        __syncthreads();   // drains staged loads; they had the whole body to land
    }

    // ---- cross-lane argmin reduce (16 lanes share each row) ----
    #pragma unroll
    for (int mask = 1; mask <= 8; mask <<= 1)
        #pragma unroll
        for (int rs = 0; rs < 2; ++rs)
            #pragma unroll
            for (int j = 0; j < 4; ++j) {
                float ov = __shfl_xor(mval[rs][j], mask, 64);
                int   oi = __shfl_xor(midx[rs][j], mask, 64);
                if (ov < mval[rs][j] || (ov == mval[rs][j] && oi < midx[rs][j])) {
                    mval[rs][j] = ov; midx[rs][j] = oi;
                }
            }
    if (l15 == 0)
        #pragma unroll
        for (int rs = 0; rs < 2; ++rs)
            #pragma unroll
            for (int j = 0; j < 4; ++j)
                idxs[w * RPW + rs * 16 + lh * 4 + j] = midx[rs][j];
    __syncthreads();

    // ---- gather: exact fp32 copy of winning code rows ----
    {
        const int row  = t >> 1;           // 0..255
        const int half = (t & 1) * 64;
        const float* src = cb + ((size_t)m * NCODE + idxs[row]) * CDIM + half;
        float*       dst = out + (size_t)(row0 + row) * XDIM + m * CDIM + half;
        #pragma unroll
        for (int i = 0; i < 16; ++i)
            *(f4*)(dst + i * 4) = *(const f4*)(src + i * 4);
    }
}

// =====================================================================
// Fallback (round-1 kernel, known-correct) for small ws_size
// =====================================================================
__global__ __launch_bounds__(512, 4)
void quant_fallback(const float* __restrict__ x, const float* __restrict__ cb,
                    float* __restrict__ out)
{
    __shared__ __align__(16) _Float16 chS[2][CHUNK][CDIM];
    __shared__ __align__(16) _Float16 clS[2][CHUNK][CDIM];
    __shared__ float  c2s[NCODE];
    __shared__ double x2p[4][128];
    __shared__ float  x2s[128];
    __shared__ int    idxs[128];

    const int t = threadIdx.x, bid = blockIdx.x;
    const int m = bid >> 8, rb = bid & 255, row0 = rb * 128;
    const int l = t & 63, w = t >> 6, l15 = l & 15, lh = l >> 4;
    const int mskr = (l & 7) * 8;

    for (int rep = 0; rep < 2; ++rep) {
        int k = t + rep * 512;
        const float* p = cb + ((size_t)m * NCODE + k) * CDIM;
        double s0 = 0, s1 = 0, s2 = 0, s3 = 0;
        for (int d = 0; d < CDIM; d += 4) {
            double v0 = p[d], v1 = p[d+1], v2 = p[d+2], v3 = p[d+3];
            s0 = fma(v0,v0,s0); s1 = fma(v1,v1,s1); s2 = fma(v2,v2,s2); s3 = fma(v3,v3,s3);
        }
        c2s[k] = (float)((s0+s1)+(s2+s3));
    }
    {
        int row = t >> 2, q = t & 3;
        const float* p = x + (size_t)(row0+row)*XDIM + m*CDIM + q*32;
        double s0 = 0, s1 = 0;
        for (int i = 0; i < 32; i += 2) { double v0=p[i], v1=p[i+1]; s0=fma(v0,v0,s0); s1=fma(v1,v1,s1); }
        x2p[q][row] = s0 + s1;
    }
    h8 xh[4], xl[4];
    {
        const float* xp = x + (size_t)(row0 + w*16 + l15)*XDIM + m*CDIM + lh*8;
        #pragma unroll
        for (int ks = 0; ks < 4; ++ks) {
            float v[8];
            *(f4*)&v[0] = *(const f4*)(xp + ks*32);
            *(f4*)&v[4] = *(const f4*)(xp + ks*32 + 4);
            #pragma unroll
            for (int i = 0; i < 8; ++i) {
                _Float16 h = (_Float16)v[i]; float r = v[i] - (float)h;
                xh[ks][i] = h; xl[ks][i] = (_Float16)(r * LO_SCALE);
            }
        }
    }
    __syncthreads();
    if (t < 128) x2s[t] = (float)((x2p[0][t]+x2p[1][t])+(x2p[2][t]+x2p[3][t]));

    const int kr = t >> 4, db = (t & 15) * 8, ew = db ^ ((kr & 7) * 8);
    auto stage_load = [&](int c, f4& a, f4& b) {
        const float* p = cb + ((size_t)m*NCODE + c*CHUNK + kr)*CDIM + db;
        a = *(const f4*)p; b = *(const f4*)(p + 4);
    };
    auto stage_write = [&](int buf, f4 a, f4 b) {
        float v[8]; *(f4*)&v[0] = a; *(f4*)&v[4] = b;
        _Float16 hh[8], ll[8];
        #pragma unroll
        for (int i = 0; i < 8; ++i) {
            _Float16 h = (_Float16)v[i]; float r = v[i] - (float)h;
            hh[i] = h; ll[i] = (_Float16)(r * LO_SCALE);
        }
        *(h8*)&chS[buf][kr][ew] = *(h8*)hh;
        *(h8*)&clS[buf][kr][ew] = *(h8*)ll;
    };

    f4 pa, pb;
    stage_load(0, pa, pb);
    stage_write(0, pa, pb);
    __syncthreads();

    float x2r[4];
    #pragma unroll
    for (int j = 0; j < 4; ++j) x2r[j] = x2s[w*16 + lh*4 + j];
    float mval[4]; int midx[4];
    #pragma unroll
    for (int j = 0; j < 4; ++j) { mval[j] = 3.0e38f; midx[j] = 0; }

    for (int c = 0; c < NCHUNK; ++c) {
        const int cur = c & 1;
        f4 na, nb;
        if (c + 1 < NCHUNK) stage_load(c + 1, na, nb);
        #pragma unroll
        for (int cf = 0; cf < 2; ++cf) {
            const int kloc = cf*16 + l15;
            f4 accH = {0,0,0,0}, accS = {0,0,0,0};
            #pragma unroll
            for (int ks = 0; ks < 4; ++ks) {
                const int e = (ks*32 + lh*8) ^ mskr;
                h8 bh = *(const h8*)&chS[cur][kloc][e];
                h8 bl = *(const h8*)&clS[cur][kloc][e];
                accH = __builtin_amdgcn_mfma_f32_16x16x32_f16(xh[ks], bh, accH, 0, 0, 0);
                accS = __builtin_amdgcn_mfma_f32_16x16x32_f16(xh[ks], bl, accS, 0, 0, 0);
                accS = __builtin_amdgcn_mfma_f32_16x16x32_f16(xl[ks], bh, accS, 0, 0, 0);
            }
            const int code = c*CHUNK + kloc;
            const float c2v = c2s[code];
            #pragma unroll
            for (int j = 0; j < 4; ++j) {
                float dot = fmaf(accS[j], LO_INV, accH[j]);
                float d2 = (x2r[j] + c2v) - 2.0f*dot;
                if (d2 < mval[j]) { mval[j] = d2; midx[j] = code; }
            }
        }
        if (c + 1 < NCHUNK) stage_write((c + 1) & 1, na, nb);
        __syncthreads();
    }
    #pragma unroll
    for (int mask = 1; mask <= 8; mask <<= 1)
        #pragma unroll
        for (int j = 0; j < 4; ++j) {
            float ov = __shfl_xor(mval[j], mask, 64);
            int   oi = __shfl_xor(midx[j], mask, 64);
            if (ov < mval[j] || (ov == mval[j] && oi < midx[j])) { mval[j] = ov; midx[j] = oi; }
        }
    if (l15 == 0)
        #pragma unroll
        for (int j = 0; j < 4; ++j) idxs[w*16 + lh*4 + j] = midx[j];
    __syncthreads();
    {
        const int row = t >> 2, qd = (t & 3) * 32;
        const float* src = cb + ((size_t)m*NCODE + idxs[row])*CDIM + qd;
        float* dst = out + (size_t)(row0+row)*XDIM + m*CDIM + qd;
        #pragma unroll
        for (int i = 0; i < 8; ++i) *(f4*)(dst + i*4) = *(const f4*)(src + i*4);
    }
}

extern "C" void kernel_launch(void* const* d_in, const int* in_sizes, int n_in,
                              void* d_out, int out_size, void* d_ws, size_t ws_size,
                              hipStream_t stream) {
    const float* x   = (const float*)d_in[0];
    const float* cb  = (const float*)d_in[1];
    float*       out = (float*)d_out;
    if (ws_size >= WS_NEED && d_ws != nullptr) {
        precompute_kernel<<<dim3(512), dim3(256), 0, stream>>>(cb, (uint8_t*)d_ws);
        quant_fast<<<dim3(NCB * (NROWS / ROWS_PB)), dim3(NTH), 0, stream>>>(
            x, cb, (const uint8_t*)d_ws, out);
    } else {
        quant_fallback<<<dim3(2048), dim3(512), 0, stream>>>(x, cb, out);
    }
}